// Round 1
// baseline (291.247 us; speedup 1.0000x reference)
//
#include <hip/hip_runtime.h>

#define WIN   11
#define PADR  5          // WIN/2
#define TILE  32
#define HALO  (TILE + WIN - 1)   // 42
#define NTHREADS 256

// ---------------------------------------------------------------------------
// Fused SSIM tile kernel: separable 11x11 Gaussian conv on 5 fields
// (x, y, x^2, y^2, x*y) + SSIM map + block partial sum.
// One block = one 32x32 output tile of one (b,c) plane.
// ---------------------------------------------------------------------------
__global__ __launch_bounds__(NTHREADS)
void ssim_tile_kernel(const float* __restrict__ x,
                      const float* __restrict__ y,
                      const float* __restrict__ kern,
                      float* __restrict__ partial,
                      int nTiles, int H, int W)
{
    __shared__ float lds_x[HALO][HALO + 1];      // 42 x 43
    __shared__ float lds_y[HALO][HALO + 1];
    __shared__ float hbuf[5][HALO][TILE + 1];    // 5 x 42 x 33
    __shared__ float wsum[NTHREADS / 64];

    const int tid   = threadIdx.x;
    const int tilesPerPlane = nTiles * nTiles;
    const int plane = blockIdx.x / tilesPerPlane;
    const int tile  = blockIdx.x % tilesPerPlane;
    const int tr    = tile / nTiles;
    const int tc    = tile % nTiles;
    const int row0  = tr * TILE - PADR;
    const int col0  = tc * TILE - PADR;

    const float* xp = x + (size_t)plane * H * W;
    const float* yp = y + (size_t)plane * H * W;

    // 1D separable weights from the (rank-1) 2D Gaussian kernel input:
    // w[i] = k2[i][5] / sqrt(k2[5][5])  =>  w[i]*w[j] == k2[i][j]
    float w[WIN];
    {
        const float cinv = rsqrtf(kern[PADR * WIN + PADR]);
        #pragma unroll
        for (int i = 0; i < WIN; ++i)
            w[i] = kern[i * WIN + PADR] * cinv;
    }

    // ---- load halo tiles (zero padding outside image) ----
    for (int idx = tid; idx < HALO * HALO; idx += NTHREADS) {
        const int r = idx / HALO;
        const int c = idx - r * HALO;
        const int gr = row0 + r;
        const int gc = col0 + c;
        const bool ok = (gr >= 0) & (gr < H) & (gc >= 0) & (gc < W);
        float vx = 0.f, vy = 0.f;
        if (ok) {
            vx = xp[(size_t)gr * W + gc];
            vy = yp[(size_t)gr * W + gc];
        }
        lds_x[r][c] = vx;
        lds_y[r][c] = vy;
    }
    __syncthreads();

    // ---- horizontal pass: 42 rows x 32 output cols, 5 fields ----
    for (int pos = tid; pos < HALO * TILE; pos += NTHREADS) {
        const int r = pos >> 5;        // /32
        const int c = pos & 31;        // %32
        float hx = 0.f, hy = 0.f, hxx = 0.f, hyy = 0.f, hxy = 0.f;
        #pragma unroll
        for (int k = 0; k < WIN; ++k) {
            const float sx = lds_x[r][c + k];
            const float sy = lds_y[r][c + k];
            const float wk = w[k];
            hx  += wk * sx;
            hy  += wk * sy;
            hxx += wk * sx * sx;
            hyy += wk * sy * sy;
            hxy += wk * sx * sy;
        }
        hbuf[0][r][c] = hx;
        hbuf[1][r][c] = hy;
        hbuf[2][r][c] = hxx;
        hbuf[3][r][c] = hyy;
        hbuf[4][r][c] = hxy;
    }
    __syncthreads();

    // ---- vertical pass: thread -> col c, 4 consecutive output rows ----
    const int c  = tid & 31;
    const int r0 = (tid >> 5) * 4;      // 8 groups * 4 rows = 32 rows

    float acc[5][4];
    #pragma unroll
    for (int f = 0; f < 5; ++f)
        #pragma unroll
        for (int j = 0; j < 4; ++j)
            acc[f][j] = 0.f;

    #pragma unroll
    for (int rr = 0; rr < WIN + 3; ++rr) {       // 14 halo rows feed 4 outputs
        float v[5];
        #pragma unroll
        for (int f = 0; f < 5; ++f)
            v[f] = hbuf[f][r0 + rr][c];
        #pragma unroll
        for (int j = 0; j < 4; ++j) {
            const int k = rr - j;
            if (k >= 0 && k < WIN) {
                const float wk = w[k];
                #pragma unroll
                for (int f = 0; f < 5; ++f)
                    acc[f][j] += wk * v[f];
            }
        }
    }

    // ---- SSIM map + local sum ----
    const float C1 = 1e-4f;   // 0.01^2
    const float C2 = 9e-4f;   // 0.03^2
    float lsum = 0.f;
    #pragma unroll
    for (int j = 0; j < 4; ++j) {
        const float mx  = acc[0][j];
        const float my  = acc[1][j];
        const float mxx = mx * mx;
        const float myy = my * my;
        const float mxy = mx * my;
        const float sxx = acc[2][j] - mxx;
        const float syy = acc[3][j] - myy;
        const float sxy = acc[4][j] - mxy;
        const float num = (2.f * mxy + C1) * (2.f * sxy + C2);
        const float den = (mxx + myy + C1) * (sxx + syy + C2);
        lsum += num / den;
    }

    // ---- block reduction ----
    #pragma unroll
    for (int off = 32; off > 0; off >>= 1)
        lsum += __shfl_down(lsum, off, 64);
    if ((tid & 63) == 0)
        wsum[tid >> 6] = lsum;
    __syncthreads();
    if (tid == 0)
        partial[blockIdx.x] = wsum[0] + wsum[1] + wsum[2] + wsum[3];
}

// ---------------------------------------------------------------------------
// Reduce per-block partials -> 1 - mean(ssim_map)
// ---------------------------------------------------------------------------
__global__ __launch_bounds__(NTHREADS)
void ssim_finalize_kernel(const float* __restrict__ partial, int n,
                          float* __restrict__ out, float invN)
{
    __shared__ float wsum[NTHREADS / 64];
    float s = 0.f;
    for (int i = threadIdx.x; i < n; i += NTHREADS)
        s += partial[i];
    #pragma unroll
    for (int off = 32; off > 0; off >>= 1)
        s += __shfl_down(s, off, 64);
    if ((threadIdx.x & 63) == 0)
        wsum[threadIdx.x >> 6] = s;
    __syncthreads();
    if (threadIdx.x == 0)
        out[0] = 1.0f - (wsum[0] + wsum[1] + wsum[2] + wsum[3]) * invN;
}

extern "C" void kernel_launch(void* const* d_in, const int* in_sizes, int n_in,
                              void* d_out, int out_size, void* d_ws, size_t ws_size,
                              hipStream_t stream)
{
    const float* x    = (const float*)d_in[0];
    const float* y    = (const float*)d_in[1];
    const float* kern = (const float*)d_in[2];
    float* out = (float*)d_out;

    const int H = 512, W = 512;
    const int planes = in_sizes[0] / (H * W);   // B*C = 64
    const int nTiles = W / TILE;                // 16
    const int nBlocks = planes * nTiles * nTiles;  // 16384

    float* partial = (float*)d_ws;   // nBlocks floats (64 KB) of scratch

    ssim_tile_kernel<<<nBlocks, NTHREADS, 0, stream>>>(
        x, y, kern, partial, nTiles, H, W);

    const float invN = 1.0f / ((float)planes * H * W);
    ssim_finalize_kernel<<<1, NTHREADS, 0, stream>>>(partial, nBlocks, out, invN);
}